// Round 10
// baseline (129.129 us; speedup 1.0000x reference)
//
#include <hip/hip_runtime.h>
#include <stdint.h>

#define D_MODEL 768
#define E3      2304
#define NCTX    2048
#define NH      12
#define HD      64
#define MROWS   4096  // 2*2048
#define NHTOT   24    // 2*12

typedef __attribute__((ext_vector_type(8))) short short8;   // 8 bf16 — MFMA x32 A/B frag
typedef __attribute__((ext_vector_type(4))) short bf16x4;   // 4 bf16 — MFMA x16 A/B frag
typedef __attribute__((ext_vector_type(4))) float f32x4;    // MFMA C/D frag

typedef __attribute__((address_space(3))) uint32_t lds_u32;
typedef __attribute__((address_space(1))) uint32_t glob_u32;

__device__ __forceinline__ void async_copy16(const void* g, void* l) {
    __builtin_amdgcn_global_load_lds((const glob_u32*)(uintptr_t)g,
                                     (lds_u32*)(uint32_t)(uintptr_t)l, 16, 0, 0);
}

__device__ __forceinline__ unsigned short f2bf(float f) {  // RNE fp32->bf16
    uint32_t u = __builtin_bit_cast(uint32_t, f);
    u += 0x7fffu + ((u >> 16) & 1u);
    return (unsigned short)(u >> 16);
}

__device__ __forceinline__ float fast_exp2(float x) {
#if __has_builtin(__builtin_amdgcn_exp2f)
    return __builtin_amdgcn_exp2f(x);
#else
    return __expf(x * 0.6931471805599453f);
#endif
}

#if __has_builtin(__builtin_amdgcn_mfma_f32_16x16x16bf16_1k)
#define HAVE_MFMA16 1
#else
#define HAVE_MFMA16 0
#endif

// ---------------- fused cast fp32 -> bf16 (x and W in one dispatch) ----------------
__global__ __launch_bounds__(256) void cast2_bf16_kernel(const float* __restrict__ a,
                                                         unsigned short* __restrict__ oa,
                                                         int na4,
                                                         const float* __restrict__ b,
                                                         unsigned short* __restrict__ ob) {
    int i = blockIdx.x * blockDim.x + threadIdx.x;
    const float4* src;
    ushort4* dst;
    int idx;
    if (i < na4) { src = (const float4*)a; dst = (ushort4*)oa; idx = i; }
    else         { src = (const float4*)b; dst = (ushort4*)ob; idx = i - na4; }
    float4 v = src[idx];
    ushort4 o;
    o.x = f2bf(v.x); o.y = f2bf(v.y); o.z = f2bf(v.z); o.w = f2bf(v.w);
    dst[idx] = o;
}

// ---------------- QKV GEMM, BM=64 x BN=128, BK=64, swizzled LDS, XCD-swizzled grid ----------------
// r6 LDS swizzle + r7 64x128 tile kept. T1 XCD swizzle kept (bijective by pure
// arithmetic: wg=(orig&7)*144+(orig>>3) covers [0,1152) exactly once; (wg>>6,wg&63)
// covers the 18x64 tile grid exactly once; per-tile math byte-identical to r7 ->
// qkv outputs bit-identical). attn's setprio — the weaker-proof r8/r9 delta — is
// the remaining failure suspect and is REVERTED this round (pairwise isolation).
// Outputs (all bf16):
//  Q -> Zq[4096][768], scaled by log2e/sqrt(768)
//  K -> Kb blocked: per (nh,kb64): elem (((ks*4+ct)*4+quadd)*16+l15k)*8+e
//  V -> Vb blocked: per (nh,kb64): elem (((ct*4+dt)*4+quadv)*16+l15d)*4+e
__global__ __launch_bounds__(256) void qkv_gemm(const unsigned short* __restrict__ A,
                                                const unsigned short* __restrict__ B,
                                                const float* __restrict__ bias,
                                                unsigned short* __restrict__ Zq,
                                                unsigned short* __restrict__ Kb,
                                                unsigned short* __restrict__ Vb) {
    __shared__ __attribute__((aligned(16))) unsigned short sA[64 * 64];
    __shared__ __attribute__((aligned(16))) unsigned short sB[128 * 64];

    const int tid  = threadIdx.x;
    const int wave = tid >> 6;
    const int lane = tid & 63;
    const int quad = lane >> 4;
    const int l15  = lane & 15;
    const int wm   = (wave >> 1) << 5;   // 0 / 32
    const int wn   = (wave & 1) << 6;    // 0 / 64

    // XCD swizzle: orig round-robins XCDs (orig&7 == xcd); give each XCD a contiguous
    // bx-major chunk of 144 blocks => ~2.25 B panels per XCD L2.
    const int orig = blockIdx.x;
    const int wg   = (orig & 7) * 144 + (orig >> 3);
    const int row0 = (wg & 63) * 64;     // by
    const int col0 = (wg >> 6) * 128;    // bx (bx-major: consecutive wg share bx)

    const int srow    = lane >> 3;                   // 0..7 (== row&7 since rbase%8==0)
    const int schunkS = ((lane & 7) ^ srow) * 8;     // swizzled source chunk offset
    const int sw      = l15 & 7;                     // read-side XOR key (row&7)

    f32x4 acc[2][4] = {};

    for (int k0 = 0; k0 < D_MODEL; k0 += 64) {
        __syncthreads();
#pragma unroll
        for (int c = 0; c < 2; ++c) {    // A: 64 rows, 2 8-row chunks per wave
            const int rbase = wave * 16 + c * 8;
            async_copy16(A + (size_t)(row0 + rbase + srow) * D_MODEL + k0 + schunkS, &sA[rbase * 64]);
        }
#pragma unroll
        for (int c = 0; c < 4; ++c) {    // B: 128 rows, 4 8-row chunks per wave
            const int rbase = wave * 32 + c * 8;
            async_copy16(B + (size_t)(col0 + rbase + srow) * D_MODEL + k0 + schunkS, &sB[rbase * 64]);
        }
        __syncthreads();

#pragma unroll
        for (int ks = 0; ks < 2; ++ks) {
            short8 aF[2], bF[4];
            const int rc = ((ks * 4 + quad) ^ sw) * 8;   // swizzled read chunk offset
#pragma unroll
            for (int i = 0; i < 2; ++i)
                aF[i] = *(const short8*)&sA[(wm + i * 16 + l15) * 64 + rc];
#pragma unroll
            for (int j = 0; j < 4; ++j)
                bF[j] = *(const short8*)&sB[(wn + j * 16 + l15) * 64 + rc];
#pragma unroll
            for (int i = 0; i < 2; ++i)
#pragma unroll
                for (int j = 0; j < 4; ++j)
                    acc[i][j] = __builtin_amdgcn_mfma_f32_16x16x32_bf16(aF[i], bF[j], acc[i][j], 0, 0, 0);
        }
    }

    // epilogue: C/D layout col=lane&15 (j dim), row=quad*4+reg (i dim)
    if (col0 < D_MODEL) {
        // ---- K -> Kb blocked ----
#pragma unroll
        for (int j = 0; j < 4; ++j) {
            const int col = col0 + wn + j * 16 + l15;
            const float bv = bias[col];
            const int h = col >> 6, d = col & 63;
            const int ks = d >> 5, quadd = (d >> 3) & 3, e = d & 7;
#pragma unroll
            for (int i = 0; i < 2; ++i) {
                const int row = row0 + wm + i * 16 + quad * 4;   // +r
                const int n = row >> 11;
                const int key = row & (NCTX - 1);
                const int kb = key >> 6;
                const int ct = ((wave >> 1) << 1) + i;            // (key%64)>>4
                const size_t base = ((size_t)((n * NH + h) * 32 + kb)) * 4096
                                  + (((ks * 4 + ct) * 4 + quadd) * 16) * 8 + e;
#pragma unroll
                for (int r = 0; r < 4; ++r)
                    Kb[base + (size_t)(quad * 4 + r) * 8] = f2bf(acc[i][j][r] + bv);
            }
        }
    } else if (col0 < 2 * D_MODEL) {
        // ---- Q -> Zq (scaled) ----
        const float zscale = 0.036084391824351615f * 1.4426950408889634f;
#pragma unroll
        for (int j = 0; j < 4; ++j) {
            const int col = col0 - D_MODEL + wn + j * 16 + l15;
            const float bv = bias[col0 + wn + j * 16 + l15];
#pragma unroll
            for (int i = 0; i < 2; ++i) {
                const int row = row0 + wm + i * 16 + quad * 4;
#pragma unroll
                for (int r = 0; r < 4; ++r)
                    Zq[(size_t)(row + r) * D_MODEL + col] = f2bf((acc[i][j][r] + bv) * zscale);
            }
        }
    } else {
        // ---- V -> Vb blocked (ushort4 over r: e=key&3) ----
#pragma unroll
        for (int j = 0; j < 4; ++j) {
            const int col = col0 + wn + j * 16 + l15;
            const float bv = bias[col];
            const int ch = col - 2 * D_MODEL;
            const int h = ch >> 6, d = ch & 63;
            const int dt = d >> 4, l15d = d & 15;
#pragma unroll
            for (int i = 0; i < 2; ++i) {
                const int row = row0 + wm + i * 16 + quad * 4;    // key base, %4==0
                const int n = row >> 11;
                const int key = row & (NCTX - 1);
                const int kb = key >> 6;
                const int ct = ((wave >> 1) << 1) + i, quadv = quad;
                ushort4 w4;
                w4.x = f2bf(acc[i][j][0] + bv);
                w4.y = f2bf(acc[i][j][1] + bv);
                w4.z = f2bf(acc[i][j][2] + bv);
                w4.w = f2bf(acc[i][j][3] + bv);
                *(ushort4*)&Vb[((size_t)((n * NH + h) * 32 + kb)) * 4096
                               + (((ct * 4 + dt) * 4 + quadv) * 16 + l15d) * 4] = w4;
            }
        }
    }
}

// ---------------- flash attention: 8-wave split-K blocks, key-slice wave roles ----------------
// BYTE-EXACT r7 attn (last passing version): no setprio, manual RNE f2bf P-packing.
// r8/r9's setprio — whose correctness argument rested on compiler-behavior
// assumptions, not math — is reverted as the remaining failure suspect.
__global__ __launch_bounds__(512, 4) void attn_kernel(const unsigned short* __restrict__ Zq,
                                                      const unsigned short* __restrict__ Kb,
                                                      const unsigned short* __restrict__ Vb,
                                                      float* __restrict__ out) {
    // sM[kv][half][buf][4096 bf16] = 64KB; doubles as the f32 reduction arena (16384 floats)
    __shared__ __attribute__((aligned(16))) unsigned short sM[2][2][2][4096];
    __shared__ float Lred[2][4][32];    // [qw][half*2+cw][qrow 0..31] partial row-sums
#if !HAVE_MFMA16
    __shared__ __attribute__((aligned(16))) unsigned short sP[8][16 * 72];
#endif

    const int tid  = threadIdx.x;
    const int wave = tid >> 6;          // 0..7
    const int half = wave >> 2;         // kb-range half
    const int w03  = wave & 3;
    const int cw   = w03 & 1;           // key 32-slice within key64 block
    const int qw   = w03 >> 1;          // q 32-half within q64 tile
    const int lane = tid & 63;
    const int quad = lane >> 4;
    const int l15  = lane & 15;
    const int b    = blockIdx.x;
    const int xcd  = b & 7;
    const int ii   = b >> 3;            // 0..95
    const int t    = 31 - ii / 3;       // heavy-first q64-tile index
    const int nh   = (ii % 3) * 8 + xcd;
    const int n    = nh / NH;
    const int h    = nh - n * NH;

    const int nA    = (t + 2) >> 1;     // iterations for half 0 (>=1)
    const int nB    = t + 1 - nA;       // iterations for half 1 (nA or nA-1)
    const int kbase = half ? nA : 0;
    const int nMy   = half ? nB : nA;

    const unsigned short* KbP = Kb + (size_t)(nh * 32) * 4096;
    const unsigned short* VbP = Vb + (size_t)(nh * 32) * 4096;

    // Q B-frags: lane holds Q[q = t*64 + qw*32 + g2*16 + l15][d = ks*32+quad*8..+7]
    const unsigned short* Qp = Zq + (size_t)(n * NCTX + t * 64 + qw * 32) * D_MODEL + h * HD;
    short8 qf[2][2];
#pragma unroll
    for (int g2 = 0; g2 < 2; ++g2)
#pragma unroll
        for (int ks = 0; ks < 2; ++ks)
            qf[g2][ks] = *(const short8*)&Qp[(size_t)(g2 * 16 + l15) * D_MODEL + ks * 32 + quad * 8];

    f32x4 o[2][4] = {};                 // [g2][dt]: partial O[q=quad*4+r][d=dt*16+l15]
    float lsum[2] = {0.0f, 0.0f};       // partial row-sums for q=g2*16+l15 (pre quad-reduce)

    // Staging: per half, its 4 waves (w03 0..3) cover the full 8KB K + 8KB V block.
#define STAGE(kbi, bufi)                                                            \
    do {                                                                            \
        const size_t gof = (size_t)(kbi) * 4096;                                    \
        _Pragma("unroll")                                                           \
        for (int c = 0; c < 2; ++c) {                                               \
            const int off = w03 * 1024 + c * 512;                                   \
            async_copy16(KbP + gof + off + lane * 8, &sM[0][half][bufi][off]);      \
            async_copy16(VbP + gof + off + lane * 8, &sM[1][half][bufi][off]);      \
        }                                                                           \
    } while (0)

    if (nMy > 0) STAGE(kbase, 0);

    for (int i = 0; i < nA; ++i) {       // nA >= nB: uniform barrier count
        __syncthreads();                 // drains staging of iter i; frees buf^1
        if (i + 1 < nMy) STAGE(kbase + i + 1, (i + 1) & 1);

        if (i < nMy) {
            const int kb  = kbase + i;
            const int buf = i & 1;

            // K A-frags for this wave's 2 key-16 sub-slices: lane-linear, conflict-free
            short8 kf[2][2];             // [ks][c2]
#pragma unroll
            for (int ks = 0; ks < 2; ++ks)
#pragma unroll
                for (int c2 = 0; c2 < 2; ++c2)
                    kf[ks][c2] = *(const short8*)&sM[0][half][buf][(ks * 4 + (cw * 2 + c2)) * 512 + lane * 8];

#if HAVE_MFMA16
            // V B-frags for this wave's slice: [c2][dt]
            bf16x4 vf[2][4];
#pragma unroll
            for (int c2 = 0; c2 < 2; ++c2)
#pragma unroll
                for (int dt = 0; dt < 4; ++dt)
                    vf[c2][dt] = *(const bf16x4*)&sM[1][half][buf][((cw * 2 + c2) * 4 + dt) * 256 + lane * 4];
#endif

            const bool diag = (kb == t);
#pragma unroll
            for (int g2 = 0; g2 < 2; ++g2) {
                // S^T = K Q^T: lane holds S[q=g2*16+l15][key = kb*64 + (cw*2+c2)*16 + quad*4 + r]
                f32x4 s[2] = {};
#pragma unroll
                for (int c2 = 0; c2 < 2; ++c2) {
                    s[c2] = __builtin_amdgcn_mfma_f32_16x16x32_bf16(kf[0][c2], qf[g2][0], s[c2], 0, 0, 0);
                    s[c2] = __builtin_amdgcn_mfma_f32_16x16x32_bf16(kf[1][c2], qf[g2][1], s[c2], 0, 0, 0);
                }

                const int qg = t * 64 + qw * 32 + g2 * 16 + l15;
#if HAVE_MFMA16
                bf16x4 pA[2];
#endif
#pragma unroll
                for (int c2 = 0; c2 < 2; ++c2) {
                    float pv[4];
#pragma unroll
                    for (int r = 0; r < 4; ++r) {
                        const int key = kb * 64 + (cw * 2 + c2) * 16 + quad * 4 + r;
                        float sv = s[c2][r];
                        if (diag && key > qg) sv = -INFINITY;
                        pv[r] = fast_exp2(sv);
                        lsum[g2] += pv[r];
                    }
#if HAVE_MFMA16
                    pA[c2][0] = (short)f2bf(pv[0]); pA[c2][1] = (short)f2bf(pv[1]);
                    pA[c2][2] = (short)f2bf(pv[2]); pA[c2][3] = (short)f2bf(pv[3]);
#else
                    ushort4 w4;
                    w4.x = f2bf(pv[0]); w4.y = f2bf(pv[1]); w4.z = f2bf(pv[2]); w4.w = f2bf(pv[3]);
                    *(ushort4*)&sP[wave][l15 * 72 + c2 * 16 + quad * 4] = w4;
#endif
                }

#if HAVE_MFMA16
                // O += P V over this wave's 32-key slice
#pragma unroll
                for (int c2 = 0; c2 < 2; ++c2)
#pragma unroll
                    for (int dt = 0; dt < 4; ++dt)
                        o[g2][dt] = __builtin_amdgcn_mfma_f32_16x16x16bf16_1k(pA[c2], vf[c2][dt], o[g2][dt], 0, 0, 0);
#else
                // fallback: sP round-trip + one x32 per (g2,dt) over the 32-key slice
                const short8 pf = *(const short8*)&sP[wave][l15 * 72 + quad * 8];
#pragma unroll
                for (int dt = 0; dt < 4; ++dt) {
                    short8 vf0;
#pragma unroll
                    for (int e = 0; e < 8; ++e) {
                        const int k0 = quad * 8 + e;              // key within the 32-slice
                        const int ct = cw * 2 + (k0 >> 4), qv = (k0 >> 2) & 3, e2 = k0 & 3;
                        vf0[e] = (short)sM[1][half][buf][(ct * 4 + dt) * 256 + qv * 64 + l15 * 4 + e2];
                    }
                    o[g2][dt] = __builtin_amdgcn_mfma_f32_16x16x32_bf16(pf, vf0, o[g2][dt], 0, 0, 0);
                }
#endif
            }
        }
    }
#undef STAGE

    // per-wave partial row-sums: reduce over quads -> every lane holds its g2 row's
    // partial sum (over this wave's key-slices) for q=qw*32+g2*16+l15
    float lr[2];
#pragma unroll
    for (int g2 = 0; g2 < 2; ++g2) {
        float l = lsum[g2];
        l += __shfl_xor(l, 16);
        l += __shfl_xor(l, 32);
        lr[g2] = l;
    }

    // ---- combine 8 partials via the 64KB sM arena (8 slots x 2048 floats) ----
    __syncthreads();                        // all loop reads of sM done
    float* R = (float*)&sM[0][0][0][0];
    const int hc = half * 2 + cw;
    {
        float* po = R + (size_t)(qw * 4 + hc) * 2048;   // [qrow 32][d 64]
#pragma unroll
        for (int g2 = 0; g2 < 2; ++g2) {
#pragma unroll
            for (int dt = 0; dt < 4; ++dt)
#pragma unroll
                for (int rr = 0; rr < 4; ++rr)
                    po[(g2 * 16 + quad * 4 + rr) * 64 + dt * 16 + l15] = o[g2][dt][rr];
            if (quad == 0) Lred[qw][hc][g2 * 16 + l15] = lr[g2];
        }
    }
    __syncthreads();
    if (half == 0) {
        // wave (0,cw,qw) finalizes q-half qw, d-columns dt in {cw*2, cw*2+1}
        const float* Rq = R + (size_t)qw * 4 * 2048;
#pragma unroll
        for (int g2 = 0; g2 < 2; ++g2)
#pragma unroll
            for (int rr = 0; rr < 4; ++rr) {
                const int qr = g2 * 16 + quad * 4 + rr;
                const float ls = Lred[qw][0][qr] + Lred[qw][1][qr] + Lred[qw][2][qr] + Lred[qw][3][qr];
                const float inv = 1.0f / ls;
                const size_t row = (size_t)n * NCTX + t * 64 + qw * 32 + qr;
#pragma unroll
                for (int dtl = 0; dtl < 2; ++dtl) {
                    const int dt = cw * 2 + dtl;
                    const int col = dt * 16 + l15;
                    const float v = Rq[0 * 2048 + qr * 64 + col] + Rq[1 * 2048 + qr * 64 + col]
                                  + Rq[2 * 2048 + qr * 64 + col] + Rq[3 * 2048 + qr * 64 + col];
                    out[row * D_MODEL + h * HD + col] = v * inv;
                }
            }
    }
}

extern "C" void kernel_launch(void* const* d_in, const int* in_sizes, int n_in,
                              void* d_out, int out_size, void* d_ws, size_t ws_size,
                              hipStream_t stream) {
    const float* x = (const float*)d_in[0];   // [2,2048,768]
    const float* W = (const float*)d_in[1];   // [2304,768]
    const float* b = (const float*)d_in[2];   // [2304]
    float* out = (float*)d_out;

    unsigned short* xb = (unsigned short*)d_ws;                    // 4096*768
    unsigned short* Wb = xb + (size_t)MROWS * D_MODEL;             // 2304*768
    unsigned short* Zq = Wb + (size_t)E3 * D_MODEL;                // 4096*768 (Q only)
    unsigned short* Kb = Zq + (size_t)MROWS * D_MODEL;             // 24*32*4096
    unsigned short* Vb = Kb + (size_t)NHTOT * 32 * 4096;           // 24*32*4096

    const int NA4 = MROWS * D_MODEL / 4;   // 786432 float4s (multiple of 256)
    const int NW4 = E3 * D_MODEL / 4;      // 442368 float4s
    cast2_bf16_kernel<<<dim3((NA4 + NW4) / 256), 256, 0, stream>>>(x, xb, NA4, W, Wb);
    qkv_gemm<<<dim3(1152), 256, 0, stream>>>(xb, Wb, b, Zq, Kb, Vb);
    attn_kernel<<<dim3(NHTOT * (NCTX / 64)), 512, 0, stream>>>(Zq, Kb, Vb, out);
}

// Round 11
// 126.641 us; speedup vs baseline: 1.0196x; 1.0196x over previous
//
#include <hip/hip_runtime.h>
#include <stdint.h>

#define D_MODEL 768
#define E3      2304
#define NCTX    2048
#define NH      12
#define HD      64
#define MROWS   4096  // 2*2048
#define NHTOT   24    // 2*12

typedef __attribute__((ext_vector_type(8))) short short8;   // 8 bf16 — MFMA x32 A/B frag
typedef __attribute__((ext_vector_type(4))) short bf16x4;   // 4 bf16 — MFMA x16 A/B frag
typedef __attribute__((ext_vector_type(4))) float f32x4;    // MFMA C/D frag

typedef __attribute__((address_space(3))) uint32_t lds_u32;
typedef __attribute__((address_space(1))) uint32_t glob_u32;

__device__ __forceinline__ void async_copy16(const void* g, void* l) {
    __builtin_amdgcn_global_load_lds((const glob_u32*)(uintptr_t)g,
                                     (lds_u32*)(uint32_t)(uintptr_t)l, 16, 0, 0);
}

__device__ __forceinline__ unsigned short f2bf(float f) {  // RNE fp32->bf16
    uint32_t u = __builtin_bit_cast(uint32_t, f);
    u += 0x7fffu + ((u >> 16) & 1u);
    return (unsigned short)(u >> 16);
}

__device__ __forceinline__ float fast_exp2(float x) {
#if __has_builtin(__builtin_amdgcn_exp2f)
    return __builtin_amdgcn_exp2f(x);
#else
    return __expf(x * 0.6931471805599453f);
#endif
}

#if __has_builtin(__builtin_amdgcn_mfma_f32_16x16x16bf16_1k)
#define HAVE_MFMA16 1
#else
#define HAVE_MFMA16 0
#endif

// ---------------- fused cast fp32 -> bf16 (x and W in one dispatch) ----------------
__global__ __launch_bounds__(256) void cast2_bf16_kernel(const float* __restrict__ a,
                                                         unsigned short* __restrict__ oa,
                                                         int na4,
                                                         const float* __restrict__ b,
                                                         unsigned short* __restrict__ ob) {
    int i = blockIdx.x * blockDim.x + threadIdx.x;
    const float4* src;
    ushort4* dst;
    int idx;
    if (i < na4) { src = (const float4*)a; dst = (ushort4*)oa; idx = i; }
    else         { src = (const float4*)b; dst = (ushort4*)ob; idx = i - na4; }
    float4 v = src[idx];
    ushort4 o;
    o.x = f2bf(v.x); o.y = f2bf(v.y); o.z = f2bf(v.z); o.w = f2bf(v.w);
    dst[idx] = o;
}

// ---------------- QKV GEMM: BM=64 x BN=128, BK=64, swizzled LDS, 2-PHASE PIPELINE ----------------
// Grid reverted to r7's 2D form (r10's XCD swizzle was -1.6us: working set is L3-fit,
// where swizzle costs ~2% per m160). This round: T3 minimum 2-phase. Old loop was
// 1-phase {barrier; STAGE(cur); barrier; compute(cur)} — staging latency fully
// serialized vs compute, 12x per block. New: double-buffered LDS (48KB), prologue
// stages buf0; per step {STAGE(kk+1 -> buf^1); compute(buf cur); __syncthreads()}.
// One barrier/step (was 2); prefetch flight hides under ~16 MFMA + frag reads; the
// barrier's implicit vmcnt(0) drain is now WANTED (prefetch must land) and has had a
// full compute phase to complete. Rotation safety: barrier at end of kk-1 orders all
// buf^1 reads (consumed by kk-1's MFMAs) before kk's STAGE writes buf^1.
// Outputs (all bf16):
//  Q -> Zq[4096][768], scaled by log2e/sqrt(768)
//  K -> Kb blocked: per (nh,kb64): elem (((ks*4+ct)*4+quadd)*16+l15k)*8+e
//  V -> Vb blocked: per (nh,kb64): elem (((ct*4+dt)*4+quadv)*16+l15d)*4+e
__global__ __launch_bounds__(256) void qkv_gemm(const unsigned short* __restrict__ A,
                                                const unsigned short* __restrict__ B,
                                                const float* __restrict__ bias,
                                                unsigned short* __restrict__ Zq,
                                                unsigned short* __restrict__ Kb,
                                                unsigned short* __restrict__ Vb) {
    __shared__ __attribute__((aligned(16))) unsigned short sA[2][64 * 64];
    __shared__ __attribute__((aligned(16))) unsigned short sB[2][128 * 64];

    const int tid  = threadIdx.x;
    const int wave = tid >> 6;
    const int lane = tid & 63;
    const int quad = lane >> 4;
    const int l15  = lane & 15;
    const int wm   = (wave >> 1) << 5;   // 0 / 32
    const int wn   = (wave & 1) << 6;    // 0 / 64
    const int row0 = blockIdx.y * 64;
    const int col0 = blockIdx.x * 128;

    const int srow    = lane >> 3;                   // 0..7 (== row&7 since rbase%8==0)
    const int schunkS = ((lane & 7) ^ srow) * 8;     // swizzled source chunk offset
    const int sw      = l15 & 7;                     // read-side XOR key (row&7)

    f32x4 acc[2][4] = {};

#define QSTAGE(kx, bufi)                                                                            \
    do {                                                                                            \
        _Pragma("unroll")                                                                           \
        for (int c = 0; c < 2; ++c) {                                                               \
            const int rbase = wave * 16 + c * 8;                                                    \
            async_copy16(A + (size_t)(row0 + rbase + srow) * D_MODEL + (kx) + schunkS,              \
                         &sA[bufi][rbase * 64]);                                                    \
        }                                                                                           \
        _Pragma("unroll")                                                                           \
        for (int c = 0; c < 4; ++c) {                                                               \
            const int rbase = wave * 32 + c * 8;                                                    \
            async_copy16(B + (size_t)(col0 + rbase + srow) * D_MODEL + (kx) + schunkS,              \
                         &sB[bufi][rbase * 64]);                                                    \
        }                                                                                           \
    } while (0)

    QSTAGE(0, 0);
    __syncthreads();                       // prologue staging complete

#pragma unroll 2
    for (int kk = 0; kk < D_MODEL / 64; ++kk) {
        const int cur = kk & 1;
        if (kk + 1 < D_MODEL / 64) QSTAGE((kk + 1) * 64, cur ^ 1);   // prefetch next K-tile

#pragma unroll
        for (int ks = 0; ks < 2; ++ks) {
            short8 aF[2], bF[4];
            const int rc = ((ks * 4 + quad) ^ sw) * 8;   // swizzled read chunk offset
#pragma unroll
            for (int i = 0; i < 2; ++i)
                aF[i] = *(const short8*)&sA[cur][(wm + i * 16 + l15) * 64 + rc];
#pragma unroll
            for (int j = 0; j < 4; ++j)
                bF[j] = *(const short8*)&sB[cur][(wn + j * 16 + l15) * 64 + rc];
#pragma unroll
            for (int i = 0; i < 2; ++i)
#pragma unroll
                for (int j = 0; j < 4; ++j)
                    acc[i][j] = __builtin_amdgcn_mfma_f32_16x16x32_bf16(aF[i], bF[j], acc[i][j], 0, 0, 0);
        }
        __syncthreads();                   // prefetch landed + all reads of cur done
    }
#undef QSTAGE

    // epilogue: C/D layout col=lane&15 (j dim), row=quad*4+reg (i dim)
    if (col0 < D_MODEL) {
        // ---- K -> Kb blocked ----
#pragma unroll
        for (int j = 0; j < 4; ++j) {
            const int col = col0 + wn + j * 16 + l15;
            const float bv = bias[col];
            const int h = col >> 6, d = col & 63;
            const int ks = d >> 5, quadd = (d >> 3) & 3, e = d & 7;
#pragma unroll
            for (int i = 0; i < 2; ++i) {
                const int row = row0 + wm + i * 16 + quad * 4;   // +r
                const int n = row >> 11;
                const int key = row & (NCTX - 1);
                const int kb = key >> 6;
                const int ct = ((wave >> 1) << 1) + i;            // (key%64)>>4
                const size_t base = ((size_t)((n * NH + h) * 32 + kb)) * 4096
                                  + (((ks * 4 + ct) * 4 + quadd) * 16) * 8 + e;
#pragma unroll
                for (int r = 0; r < 4; ++r)
                    Kb[base + (size_t)(quad * 4 + r) * 8] = f2bf(acc[i][j][r] + bv);
            }
        }
    } else if (col0 < 2 * D_MODEL) {
        // ---- Q -> Zq (scaled) ----
        const float zscale = 0.036084391824351615f * 1.4426950408889634f;
#pragma unroll
        for (int j = 0; j < 4; ++j) {
            const int col = col0 - D_MODEL + wn + j * 16 + l15;
            const float bv = bias[col0 + wn + j * 16 + l15];
#pragma unroll
            for (int i = 0; i < 2; ++i) {
                const int row = row0 + wm + i * 16 + quad * 4;
#pragma unroll
                for (int r = 0; r < 4; ++r)
                    Zq[(size_t)(row + r) * D_MODEL + col] = f2bf((acc[i][j][r] + bv) * zscale);
            }
        }
    } else {
        // ---- V -> Vb blocked (ushort4 over r: e=key&3) ----
#pragma unroll
        for (int j = 0; j < 4; ++j) {
            const int col = col0 + wn + j * 16 + l15;
            const float bv = bias[col];
            const int ch = col - 2 * D_MODEL;
            const int h = ch >> 6, d = ch & 63;
            const int dt = d >> 4, l15d = d & 15;
#pragma unroll
            for (int i = 0; i < 2; ++i) {
                const int row = row0 + wm + i * 16 + quad * 4;    // key base, %4==0
                const int n = row >> 11;
                const int key = row & (NCTX - 1);
                const int kb = key >> 6;
                const int ct = ((wave >> 1) << 1) + i, quadv = quad;
                ushort4 w4;
                w4.x = f2bf(acc[i][j][0] + bv);
                w4.y = f2bf(acc[i][j][1] + bv);
                w4.z = f2bf(acc[i][j][2] + bv);
                w4.w = f2bf(acc[i][j][3] + bv);
                *(ushort4*)&Vb[((size_t)((n * NH + h) * 32 + kb)) * 4096
                               + (((ct * 4 + dt) * 4 + quadv) * 16 + l15d) * 4] = w4;
            }
        }
    }
}

// ---------------- flash attention: 8-wave split-K blocks, key-slice wave roles ----------------
// BYTE-EXACT passing version (r7/r10): no setprio (r9 convicted it as the correctness
// breaker), manual RNE f2bf P-packing.
__global__ __launch_bounds__(512, 4) void attn_kernel(const unsigned short* __restrict__ Zq,
                                                      const unsigned short* __restrict__ Kb,
                                                      const unsigned short* __restrict__ Vb,
                                                      float* __restrict__ out) {
    // sM[kv][half][buf][4096 bf16] = 64KB; doubles as the f32 reduction arena (16384 floats)
    __shared__ __attribute__((aligned(16))) unsigned short sM[2][2][2][4096];
    __shared__ float Lred[2][4][32];    // [qw][half*2+cw][qrow 0..31] partial row-sums
#if !HAVE_MFMA16
    __shared__ __attribute__((aligned(16))) unsigned short sP[8][16 * 72];
#endif

    const int tid  = threadIdx.x;
    const int wave = tid >> 6;          // 0..7
    const int half = wave >> 2;         // kb-range half
    const int w03  = wave & 3;
    const int cw   = w03 & 1;           // key 32-slice within key64 block
    const int qw   = w03 >> 1;          // q 32-half within q64 tile
    const int lane = tid & 63;
    const int quad = lane >> 4;
    const int l15  = lane & 15;
    const int b    = blockIdx.x;
    const int xcd  = b & 7;
    const int ii   = b >> 3;            // 0..95
    const int t    = 31 - ii / 3;       // heavy-first q64-tile index
    const int nh   = (ii % 3) * 8 + xcd;
    const int n    = nh / NH;
    const int h    = nh - n * NH;

    const int nA    = (t + 2) >> 1;     // iterations for half 0 (>=1)
    const int nB    = t + 1 - nA;       // iterations for half 1 (nA or nA-1)
    const int kbase = half ? nA : 0;
    const int nMy   = half ? nB : nA;

    const unsigned short* KbP = Kb + (size_t)(nh * 32) * 4096;
    const unsigned short* VbP = Vb + (size_t)(nh * 32) * 4096;

    // Q B-frags: lane holds Q[q = t*64 + qw*32 + g2*16 + l15][d = ks*32+quad*8..+7]
    const unsigned short* Qp = Zq + (size_t)(n * NCTX + t * 64 + qw * 32) * D_MODEL + h * HD;
    short8 qf[2][2];
#pragma unroll
    for (int g2 = 0; g2 < 2; ++g2)
#pragma unroll
        for (int ks = 0; ks < 2; ++ks)
            qf[g2][ks] = *(const short8*)&Qp[(size_t)(g2 * 16 + l15) * D_MODEL + ks * 32 + quad * 8];

    f32x4 o[2][4] = {};                 // [g2][dt]: partial O[q=quad*4+r][d=dt*16+l15]
    float lsum[2] = {0.0f, 0.0f};       // partial row-sums for q=g2*16+l15 (pre quad-reduce)

    // Staging: per half, its 4 waves (w03 0..3) cover the full 8KB K + 8KB V block.
#define STAGE(kbi, bufi)                                                            \
    do {                                                                            \
        const size_t gof = (size_t)(kbi) * 4096;                                    \
        _Pragma("unroll")                                                           \
        for (int c = 0; c < 2; ++c) {                                               \
            const int off = w03 * 1024 + c * 512;                                   \
            async_copy16(KbP + gof + off + lane * 8, &sM[0][half][bufi][off]);      \
            async_copy16(VbP + gof + off + lane * 8, &sM[1][half][bufi][off]);      \
        }                                                                           \
    } while (0)

    if (nMy > 0) STAGE(kbase, 0);

    for (int i = 0; i < nA; ++i) {       // nA >= nB: uniform barrier count
        __syncthreads();                 // drains staging of iter i; frees buf^1
        if (i + 1 < nMy) STAGE(kbase + i + 1, (i + 1) & 1);

        if (i < nMy) {
            const int kb  = kbase + i;
            const int buf = i & 1;

            // K A-frags for this wave's 2 key-16 sub-slices: lane-linear, conflict-free
            short8 kf[2][2];             // [ks][c2]
#pragma unroll
            for (int ks = 0; ks < 2; ++ks)
#pragma unroll
                for (int c2 = 0; c2 < 2; ++c2)
                    kf[ks][c2] = *(const short8*)&sM[0][half][buf][(ks * 4 + (cw * 2 + c2)) * 512 + lane * 8];

#if HAVE_MFMA16
            // V B-frags for this wave's slice: [c2][dt]
            bf16x4 vf[2][4];
#pragma unroll
            for (int c2 = 0; c2 < 2; ++c2)
#pragma unroll
                for (int dt = 0; dt < 4; ++dt)
                    vf[c2][dt] = *(const bf16x4*)&sM[1][half][buf][((cw * 2 + c2) * 4 + dt) * 256 + lane * 4];
#endif

            const bool diag = (kb == t);
#pragma unroll
            for (int g2 = 0; g2 < 2; ++g2) {
                // S^T = K Q^T: lane holds S[q=g2*16+l15][key = kb*64 + (cw*2+c2)*16 + quad*4 + r]
                f32x4 s[2] = {};
#pragma unroll
                for (int c2 = 0; c2 < 2; ++c2) {
                    s[c2] = __builtin_amdgcn_mfma_f32_16x16x32_bf16(kf[0][c2], qf[g2][0], s[c2], 0, 0, 0);
                    s[c2] = __builtin_amdgcn_mfma_f32_16x16x32_bf16(kf[1][c2], qf[g2][1], s[c2], 0, 0, 0);
                }

                const int qg = t * 64 + qw * 32 + g2 * 16 + l15;
#if HAVE_MFMA16
                bf16x4 pA[2];
#endif
#pragma unroll
                for (int c2 = 0; c2 < 2; ++c2) {
                    float pv[4];
#pragma unroll
                    for (int r = 0; r < 4; ++r) {
                        const int key = kb * 64 + (cw * 2 + c2) * 16 + quad * 4 + r;
                        float sv = s[c2][r];
                        if (diag && key > qg) sv = -INFINITY;
                        pv[r] = fast_exp2(sv);
                        lsum[g2] += pv[r];
                    }
#if HAVE_MFMA16
                    pA[c2][0] = (short)f2bf(pv[0]); pA[c2][1] = (short)f2bf(pv[1]);
                    pA[c2][2] = (short)f2bf(pv[2]); pA[c2][3] = (short)f2bf(pv[3]);
#else
                    ushort4 w4;
                    w4.x = f2bf(pv[0]); w4.y = f2bf(pv[1]); w4.z = f2bf(pv[2]); w4.w = f2bf(pv[3]);
                    *(ushort4*)&sP[wave][l15 * 72 + c2 * 16 + quad * 4] = w4;
#endif
                }

#if HAVE_MFMA16
                // O += P V over this wave's 32-key slice
#pragma unroll
                for (int c2 = 0; c2 < 2; ++c2)
#pragma unroll
                    for (int dt = 0; dt < 4; ++dt)
                        o[g2][dt] = __builtin_amdgcn_mfma_f32_16x16x16bf16_1k(pA[c2], vf[c2][dt], o[g2][dt], 0, 0, 0);
#else
                // fallback: sP round-trip + one x32 per (g2,dt) over the 32-key slice
                const short8 pf = *(const short8*)&sP[wave][l15 * 72 + quad * 8];
#pragma unroll
                for (int dt = 0; dt < 4; ++dt) {
                    short8 vf0;
#pragma unroll
                    for (int e = 0; e < 8; ++e) {
                        const int k0 = quad * 8 + e;              // key within the 32-slice
                        const int ct = cw * 2 + (k0 >> 4), qv = (k0 >> 2) & 3, e2 = k0 & 3;
                        vf0[e] = (short)sM[1][half][buf][(ct * 4 + dt) * 256 + qv * 64 + l15 * 4 + e2];
                    }
                    o[g2][dt] = __builtin_amdgcn_mfma_f32_16x16x32_bf16(pf, vf0, o[g2][dt], 0, 0, 0);
                }
#endif
            }
        }
    }
#undef STAGE

    // per-wave partial row-sums: reduce over quads -> every lane holds its g2 row's
    // partial sum (over this wave's key-slices) for q=qw*32+g2*16+l15
    float lr[2];
#pragma unroll
    for (int g2 = 0; g2 < 2; ++g2) {
        float l = lsum[g2];
        l += __shfl_xor(l, 16);
        l += __shfl_xor(l, 32);
        lr[g2] = l;
    }

    // ---- combine 8 partials via the 64KB sM arena (8 slots x 2048 floats) ----
    __syncthreads();                        // all loop reads of sM done
    float* R = (float*)&sM[0][0][0][0];
    const int hc = half * 2 + cw;
    {
        float* po = R + (size_t)(qw * 4 + hc) * 2048;   // [qrow 32][d 64]
#pragma unroll
        for (int g2 = 0; g2 < 2; ++g2) {
#pragma unroll
            for (int dt = 0; dt < 4; ++dt)
#pragma unroll
                for (int rr = 0; rr < 4; ++rr)
                    po[(g2 * 16 + quad * 4 + rr) * 64 + dt * 16 + l15] = o[g2][dt][rr];
            if (quad == 0) Lred[qw][hc][g2 * 16 + l15] = lr[g2];
        }
    }
    __syncthreads();
    if (half == 0) {
        // wave (0,cw,qw) finalizes q-half qw, d-columns dt in {cw*2, cw*2+1}
        const float* Rq = R + (size_t)qw * 4 * 2048;
#pragma unroll
        for (int g2 = 0; g2 < 2; ++g2)
#pragma unroll
            for (int rr = 0; rr < 4; ++rr) {
                const int qr = g2 * 16 + quad * 4 + rr;
                const float ls = Lred[qw][0][qr] + Lred[qw][1][qr] + Lred[qw][2][qr] + Lred[qw][3][qr];
                const float inv = 1.0f / ls;
                const size_t row = (size_t)n * NCTX + t * 64 + qw * 32 + qr;
#pragma unroll
                for (int dtl = 0; dtl < 2; ++dtl) {
                    const int dt = cw * 2 + dtl;
                    const int col = dt * 16 + l15;
                    const float v = Rq[0 * 2048 + qr * 64 + col] + Rq[1 * 2048 + qr * 64 + col]
                                  + Rq[2 * 2048 + qr * 64 + col] + Rq[3 * 2048 + qr * 64 + col];
                    out[row * D_MODEL + h * HD + col] = v * inv;
                }
            }
    }
}

extern "C" void kernel_launch(void* const* d_in, const int* in_sizes, int n_in,
                              void* d_out, int out_size, void* d_ws, size_t ws_size,
                              hipStream_t stream) {
    const float* x = (const float*)d_in[0];   // [2,2048,768]
    const float* W = (const float*)d_in[1];   // [2304,768]
    const float* b = (const float*)d_in[2];   // [2304]
    float* out = (float*)d_out;

    unsigned short* xb = (unsigned short*)d_ws;                    // 4096*768
    unsigned short* Wb = xb + (size_t)MROWS * D_MODEL;             // 2304*768
    unsigned short* Zq = Wb + (size_t)E3 * D_MODEL;                // 4096*768 (Q only)
    unsigned short* Kb = Zq + (size_t)MROWS * D_MODEL;             // 24*32*4096
    unsigned short* Vb = Kb + (size_t)NHTOT * 32 * 4096;           // 24*32*4096

    const int NA4 = MROWS * D_MODEL / 4;   // 786432 float4s (multiple of 256)
    const int NW4 = E3 * D_MODEL / 4;      // 442368 float4s
    cast2_bf16_kernel<<<dim3((NA4 + NW4) / 256), 256, 0, stream>>>(x, xb, NA4, W, Wb);
    qkv_gemm<<<dim3(E3 / 128, MROWS / 64), 256, 0, stream>>>(xb, Wb, b, Zq, Kb, Vb);
    attn_kernel<<<dim3(NHTOT * (NCTX / 64)), 512, 0, stream>>>(Zq, Kb, Vb, out);
}